// Round 1
// baseline (1984.202 us; speedup 1.0000x reference)
//
#include <hip/hip_runtime.h>
#include <cstdint>
#include <cstddef>

#define HW 4096
#define CDIM 768

typedef unsigned short u16;
typedef __attribute__((ext_vector_type(8))) short short8;
typedef __attribute__((ext_vector_type(4))) float f32x4;

__device__ __forceinline__ float bf2f(u16 u) { return __uint_as_float(((unsigned)u) << 16); }
__device__ __forceinline__ u16 f2bf(float f) {
    unsigned u = __float_as_uint(f);
    unsigned r = (u + 0x7fffu + ((u >> 16) & 1u)) >> 16;
    return (u16)r;
}

// ---------------------------------------------------------------- GEMM core
// C[M=4096, N][fp32 acc] = A'[4096, K] @ B^T where B is [N][768-per-sub] bf16 row-major.
// Tile 128x128, BK=32, 4 waves (2x2), each wave 4x4 frags of 16x16x32 bf16 MFMA.
constexpr int BM = 128, BN = 128, BK = 32, LDP = 40;

enum GMode { G_CONV = 0, G_DEFORM = 1, G_PROJ = 2, G_SPAT = 3 };

struct ProjP {
    const u16* b1[5];
    const u16* b2[5];
    int ch[5];
    int choff[5];
};

template <int MODE>
__launch_bounds__(256, 2)
__global__ void k_gemm(const u16* __restrict__ xb,    // [5][4096][768] bf16 (conv/deform A, proj A2)
                       const u16* __restrict__ blkA,  // proj A1 base / spat A (xatt)
                       const u16* __restrict__ Wt,    // conv/deform B [9][768][768] / spat B (spqb)
                       const int4* __restrict__ idx4, // [5][9][4096] row offsets (pre *768)
                       const float4* __restrict__ w4, // [5][9][4096] fused weights
                       const float* __restrict__ bias,
                       u16* __restrict__ outb,        // bf16 out (conv om / deform dout)
                       float* __restrict__ outf,      // fp32 out (Xcat / P2)
                       ProjP pp) {
    const int z = blockIdx.z;
    const int m0 = blockIdx.x * BM;
    const int n0 = blockIdx.y * BN;

    int Nrows, nsteps, choff = 0, ldo = CDIM;
    const u16 *A1 = nullptr, *A2 = nullptr, *B1 = nullptr, *B2 = nullptr;
    const int4* idxz = nullptr;
    const float4* w4z = nullptr;

    if constexpr (MODE == G_CONV) {
        A1 = xb + (size_t)z * HW * CDIM; B1 = Wt; Nrows = 768; nsteps = 216;
    } else if constexpr (MODE == G_DEFORM) {
        A1 = xb + (size_t)z * HW * CDIM; B1 = Wt; Nrows = 768; nsteps = 216;
        idxz = idx4 + (size_t)z * 9 * 4096;
        w4z = w4 + (size_t)z * 9 * 4096;
    } else if constexpr (MODE == G_PROJ) {
        A1 = blkA + (size_t)z * HW * CDIM;
        A2 = xb + (size_t)z * HW * CDIM;
        B1 = pp.b1[z]; B2 = pp.b2[z];
        Nrows = pp.ch[z]; choff = pp.choff[z];
        nsteps = B2 ? 48 : 24;
        if (n0 >= Nrows) return;
    } else { // G_SPAT
        A1 = blkA; B1 = Wt; Nrows = 384; nsteps = 24; ldo = 384;
        if (n0 >= Nrows) return;
    }

    __shared__ __align__(16) u16 As[BM * LDP];
    __shared__ __align__(16) u16 Bs[BN * LDP];

    const int t = threadIdx.x;
    const int row = t >> 1;
    const int seg = t & 1;
    const int lane = t & 63;
    const int wid = t >> 6;
    const int wrow = (wid >> 1) * 64, wcol = (wid & 1) * 64;
    const int lm = lane & 15;
    const int lk = (lane >> 4) * 8;
    const int quad = lane >> 4;

    f32x4 acc[4][4];
#pragma unroll
    for (int i = 0; i < 4; i++)
#pragma unroll
        for (int j = 0; j < 4; j++) acc[i][j] = (f32x4){0.f, 0.f, 0.f, 0.f};

    for (int step = 0; step < nsteps; ++step) {
        const int sub = step / 24;          // tap (conv/deform) or K-half (proj)
        const int cc0 = (step % 24) * 32;   // c offset within 768
        const int cb = cc0 + seg * 16;

        __syncthreads();
        // ---- stage A: 128 rows x 32 bf16 ----
        uint4 av0, av1;
        if constexpr (MODE == G_CONV) {
            int p = m0 + row;
            int ky = sub / 3 - 1, kx = sub % 3 - 1;
            int h = (p >> 6) + ky, w = (p & 63) + kx;
            if (h >= 0 && h < 64 && w >= 0 && w < 64) {
                const u16* s = A1 + (size_t)(h * 64 + w) * CDIM + cb;
                av0 = *(const uint4*)s;
                av1 = *(const uint4*)(s + 8);
            } else {
                av0 = make_uint4(0, 0, 0, 0); av1 = av0;
            }
        } else if constexpr (MODE == G_DEFORM) {
            int p = m0 + row;
            int4 iv = idxz[sub * 4096 + p];
            float4 wv = w4z[sub * 4096 + p];
            const u16* r0 = A1 + iv.x + cb;
            const u16* r1 = A1 + iv.y + cb;
            const u16* r2 = A1 + iv.z + cb;
            const u16* r3 = A1 + iv.w + cb;
            u16 tmp[16];
#pragma unroll
            for (int u = 0; u < 2; u++) {
                uint4 a0 = *(const uint4*)(r0 + u * 8);
                uint4 a1 = *(const uint4*)(r1 + u * 8);
                uint4 a2 = *(const uint4*)(r2 + u * 8);
                uint4 a3 = *(const uint4*)(r3 + u * 8);
                const u16* p0 = (const u16*)&a0;
                const u16* p1 = (const u16*)&a1;
                const u16* p2 = (const u16*)&a2;
                const u16* p3 = (const u16*)&a3;
#pragma unroll
                for (int e = 0; e < 8; e++) {
                    float f = wv.x * bf2f(p0[e]) + wv.y * bf2f(p1[e]) +
                              wv.z * bf2f(p2[e]) + wv.w * bf2f(p3[e]);
                    tmp[u * 8 + e] = f2bf(f);
                }
            }
            av0 = *(uint4*)tmp;
            av1 = *(uint4*)(tmp + 8);
        } else { // PROJ / SPAT: plain
            const u16* Ab = (sub == 0) ? A1 : A2;
            const u16* s = Ab + (size_t)(m0 + row) * CDIM + cb;
            av0 = *(const uint4*)s;
            av1 = *(const uint4*)(s + 8);
        }
        {
            u16* d = &As[row * LDP + seg * 16];
            *(uint4*)d = av0;
            *(uint4*)(d + 8) = av1;
        }
        // ---- stage B ----
        {
            const u16* Bb;
            if constexpr (MODE == G_CONV || MODE == G_DEFORM)
                Bb = B1 + (size_t)sub * CDIM * CDIM;
            else if constexpr (MODE == G_PROJ)
                Bb = (sub == 0) ? B1 : B2;
            else
                Bb = B1;
            int nr = n0 + row;
            uint4 bv0, bv1;
            if (nr < Nrows) {
                const u16* s = Bb + (size_t)nr * CDIM + cb;
                bv0 = *(const uint4*)s;
                bv1 = *(const uint4*)(s + 8);
            } else {
                bv0 = make_uint4(0, 0, 0, 0); bv1 = bv0;
            }
            u16* d = &Bs[row * LDP + seg * 16];
            *(uint4*)d = bv0;
            *(uint4*)(d + 8) = bv1;
        }
        __syncthreads();
        // ---- MFMA ----
        short8 af[4], bff[4];
#pragma unroll
        for (int i = 0; i < 4; i++) af[i] = *(const short8*)&As[(wrow + i * 16 + lm) * LDP + lk];
#pragma unroll
        for (int j = 0; j < 4; j++) bff[j] = *(const short8*)&Bs[(wcol + j * 16 + lm) * LDP + lk];
#pragma unroll
        for (int i = 0; i < 4; i++)
#pragma unroll
            for (int j = 0; j < 4; j++)
                acc[i][j] = __builtin_amdgcn_mfma_f32_16x16x32_bf16(af[i], bff[j], acc[i][j], 0, 0, 0);
    }

    // ---- epilogue ----
    if constexpr (MODE == G_CONV || MODE == G_DEFORM) {
        u16* outz = outb + (size_t)z * HW * CDIM;
#pragma unroll
        for (int j = 0; j < 4; j++) {
            int gc = n0 + wcol + j * 16 + lm;
            float bv = bias[gc];
#pragma unroll
            for (int i = 0; i < 4; i++)
#pragma unroll
                for (int r = 0; r < 4; r++) {
                    int gr = m0 + wrow + i * 16 + quad * 4 + r;
                    outz[(size_t)gr * CDIM + gc] = f2bf(acc[i][j][r] + bv);
                }
        }
    } else {
#pragma unroll
        for (int j = 0; j < 4; j++) {
            int gc = n0 + wcol + j * 16 + lm;
            if (gc < Nrows) {
#pragma unroll
                for (int i = 0; i < 4; i++)
#pragma unroll
                    for (int r = 0; r < 4; r++) {
                        int gr = m0 + wrow + i * 16 + quad * 4 + r;
                        outf[(size_t)gr * ldo + choff + gc] = acc[i][j][r];
                    }
            }
        }
    }
}

// ---------------------------------------------------------------- prep kernels
struct Ptr5 { const float* p[5]; };

__global__ void k_prep_x(Ptr5 xs, u16* __restrict__ xb) {
    int z = blockIdx.y;
    size_t i = ((size_t)blockIdx.x * 256 + threadIdx.x) * 8;
    const float* s = xs.p[z] + i;
    float4 a = ((const float4*)s)[0];
    float4 b = ((const float4*)s)[1];
    u16 o[8] = {f2bf(a.x), f2bf(a.y), f2bf(a.z), f2bf(a.w),
                f2bf(b.x), f2bf(b.y), f2bf(b.z), f2bf(b.w)};
    *(uint4*)(xb + (size_t)z * HW * CDIM + i) = *(uint4*)o;
}

__global__ void k_prep_wt(const float* __restrict__ cw, u16* __restrict__ Wt) {
    int o = blockIdx.x;
    for (int c = threadIdx.x; c < 768; c += 256) {
        const float* s = cw + ((size_t)o * 768 + c) * 9;
#pragma unroll
        for (int k = 0; k < 9; k++)
            Wt[(size_t)k * 768 * 768 + (size_t)o * 768 + c] = f2bf(s[k]);
    }
}

struct WbP { const float* src[9]; u16* dst[9]; int n[9]; };

__global__ void k_prep_wb(WbP wp) {
    int m = blockIdx.y;
    int i = (blockIdx.x * 256 + threadIdx.x) * 4;
    if (i >= wp.n[m]) return;
    float4 v = *(const float4*)(wp.src[m] + i);
    u16* d = wp.dst[m] + i;
    d[0] = f2bf(v.x); d[1] = f2bf(v.y); d[2] = f2bf(v.z); d[3] = f2bf(v.w);
}

// ---------------------------------------------------------------- offset / mask
__global__ void k_offmask1(const u16* __restrict__ om, const float* __restrict__ off_w,
                           const float* __restrict__ off_b, const float* __restrict__ msk_w,
                           const float* __restrict__ msk_b, float* __restrict__ offs,
                           float* __restrict__ msoft) {
    int z = blockIdx.y;
    int wid = threadIdx.x >> 6, lane = threadIdx.x & 63;
    int p = blockIdx.x * 4 + wid;
    const u16* r = om + (size_t)z * HW * CDIM + (size_t)p * CDIM;
    float v[12];
#pragma unroll
    for (int j = 0; j < 12; j++) v[j] = bf2f(r[lane + 64 * j]);
    float lg[9];
#pragma unroll
    for (int qq = 0; qq < 27; qq++) {
        const float* wr = (qq < 18) ? (off_w + qq * 768) : (msk_w + (qq - 18) * 768);
        float s = 0.f;
#pragma unroll
        for (int j = 0; j < 12; j++) s += v[j] * wr[lane + 64 * j];
#pragma unroll
        for (int o = 32; o > 0; o >>= 1) s += __shfl_xor(s, o, 64);
        if (qq < 18) {
            if (lane == qq) offs[((size_t)z * HW + p) * 18 + qq] = s + off_b[qq];
        } else {
            lg[qq - 18] = s + msk_b[qq - 18];
        }
    }
    float mx = -1e30f;
#pragma unroll
    for (int j = 0; j < 9; j++) mx = fmaxf(mx, lg[j]);
    float sum = 0.f;
#pragma unroll
    for (int j = 0; j < 9; j++) { lg[j] = expf(lg[j] - mx); sum += lg[j]; }
    float inv = 1.f / sum;
#pragma unroll
    for (int j = 0; j < 9; j++)
        if (lane == j) msoft[(size_t)z * 36864 + p * 9 + j] = lg[j] * inv;
}

__device__ __forceinline__ int cidx(int y, int x) {
    int yc = min(max(y, 0), 63), xc = min(max(x, 0), 63);
    return (yc * 64 + xc) * CDIM;
}
__device__ __forceinline__ float cval(int y, int x) {
    return (y >= 0 && y < 64 && x >= 0 && x < 64) ? 1.f : 0.f;
}

__global__ void k_offmask2(const float* __restrict__ offs, const float* __restrict__ msoft,
                           int4* __restrict__ idx4o, float4* __restrict__ w4o) {
    int id = blockIdx.x * 256 + threadIdx.x;
    int z = id / 36864, r = id % 36864, k = r >> 12, p = r & 4095;
    const float* ofz = offs + ((size_t)z * HW + p) * 18;
    float dy = ofz[2 * k], dx = ofz[2 * k + 1];
    float mk = msoft[(size_t)z * 36864 + k * 4096 + p];
    int h = p >> 6, w = p & 63;
    float py = (float)(h - 1 + k / 3) + dy;
    float px = (float)(w - 1 + k % 3) + dx;
    float y0f = floorf(py), x0f = floorf(px);
    int y0 = (int)y0f, x0 = (int)x0f;
    float wy1 = py - y0f, wx1 = px - x0f, wy0 = 1.f - wy1, wx0 = 1.f - wx1;
    idx4o[id] = make_int4(cidx(y0, x0), cidx(y0, x0 + 1), cidx(y0 + 1, x0), cidx(y0 + 1, x0 + 1));
    w4o[id] = make_float4(wy0 * wx0 * cval(y0, x0) * mk, wy0 * wx1 * cval(y0, x0 + 1) * mk,
                          wy1 * wx0 * cval(y0 + 1, x0) * mk, wy1 * wx1 * cval(y0 + 1, x0 + 1) * mk);
}

// ---------------------------------------------------------------- batchnorm
__global__ void k_bnstats(const u16* __restrict__ dout, float* __restrict__ mu,
                          float* __restrict__ rs) {
    int z = blockIdx.y;
    int c = blockIdx.x * 64 + threadIdx.x;
    int ty = threadIdx.y;
    const u16* d = dout + (size_t)z * HW * CDIM + c;
    float s1 = 0.f, s2 = 0.f;
    for (int p = ty; p < 4096; p += 8) {
        float v = bf2f(d[(size_t)p * CDIM]);
        s1 += v; s2 += v * v;
    }
    __shared__ float l1[8][64], l2[8][64];
    l1[ty][threadIdx.x] = s1; l2[ty][threadIdx.x] = s2;
    __syncthreads();
    if (ty == 0) {
        for (int y = 1; y < 8; y++) { s1 += l1[y][threadIdx.x]; s2 += l2[y][threadIdx.x]; }
        float m = s1 / 4096.f;
        float var = s2 / 4096.f - m * m;
        mu[z * 768 + c] = m;
        rs[z * 768 + c] = rsqrtf(var + 1e-5f);
    }
}

__global__ void k_bnapply(const u16* __restrict__ dout, const float* __restrict__ mu,
                          const float* __restrict__ rs, const float* __restrict__ g,
                          const float* __restrict__ b, u16* __restrict__ blk) {
    size_t i = ((size_t)blockIdx.x * 256 + threadIdx.x) * 8;
    int c = (int)(i % CDIM);
    int z = (int)(i / ((size_t)HW * CDIM));
    const float* muz = mu + z * 768;
    const float* rsz = rs + z * 768;
    uint4 in = *(const uint4*)(dout + i);
    const u16* u = (const u16*)&in;
    u16 o[8];
#pragma unroll
    for (int e = 0; e < 8; e++) {
        int ce = c + e;
        float v = (bf2f(u[e]) - muz[ce]) * rsz[ce] * g[ce] + b[ce];
        o[e] = f2bf(fmaxf(v, 0.f));
    }
    *(uint4*)(blk + i) = *(uint4*)o;
}

// ---------------------------------------------------------------- CAM
__global__ void k_q(const float* __restrict__ X, const float* __restrict__ chq,
                    float* __restrict__ q) {
    int wid = threadIdx.x >> 6, lane = threadIdx.x & 63;
    int p = blockIdx.x * 4 + wid;
    const float* xr = X + (size_t)p * CDIM;
    float s = 0.f;
#pragma unroll
    for (int j = 0; j < 12; j++) s += xr[lane + 64 * j] * chq[lane + 64 * j];
#pragma unroll
    for (int o = 32; o > 0; o >>= 1) s += __shfl_xor(s, o, 64);
    if (lane == 0) q[p] = s;
}

__global__ void k_soft4096(const float* __restrict__ q, float* __restrict__ sqn,
                           float* __restrict__ xq) {
    __shared__ float red[4];
    int tid = threadIdx.x, lane = tid & 63, wid = tid >> 6;
    float m = -1e30f;
    for (int i = tid; i < 4096; i += 256) m = fmaxf(m, q[i]);
    for (int o = 32; o > 0; o >>= 1) m = fmaxf(m, __shfl_xor(m, o, 64));
    if (lane == 0) red[wid] = m;
    __syncthreads();
    float bm = fmaxf(fmaxf(red[0], red[1]), fmaxf(red[2], red[3]));
    __syncthreads();
    float s = 0.f;
    for (int i = tid; i < 4096; i += 256) {
        float e = expf(q[i] - bm);
        sqn[i] = e; s += e;
    }
    for (int o = 32; o > 0; o >>= 1) s += __shfl_xor(s, o, 64);
    if (lane == 0) red[wid] = s;
    __syncthreads();
    float inv = 1.f / (red[0] + red[1] + red[2] + red[3]);
    for (int i = tid; i < 4096; i += 256) sqn[i] *= inv;
    for (int c = tid; c < 768; c += 256) xq[c] = 0.f;
}

__global__ void k_xq(const float* __restrict__ X, const float* __restrict__ sqn,
                     float* __restrict__ xq) {
    int p0 = blockIdx.x * 512;
    for (int c = threadIdx.x; c < 768; c += 256) {
        float a = 0.f;
        for (int p = p0; p < p0 + 512; p++) a += sqn[p] * X[(size_t)p * CDIM + c];
        atomicAdd(&xq[c], a);
    }
}

__global__ void k_cam4(const float* __restrict__ chv, const float* __restrict__ chz,
                       const float* __restrict__ xq, const float* __restrict__ lng,
                       const float* __restrict__ lnb, float* __restrict__ sgate) {
    __shared__ float wvq[384];
    __shared__ float wzv[768];
    __shared__ float red[12];
    int tid = threadIdx.x, lane = tid & 63, wid = tid >> 6;
    {
        float s = 0.f;
        const float* r = chv + (size_t)tid * 768;
        for (int j = 0; j < 768; j++) s += r[j] * xq[j];
        wvq[tid] = s;
    }
    __syncthreads();
    for (int c = tid; c < 768; c += 384) {
        float s = 0.f;
        const float* r = chz + (size_t)c * 384;
        for (int o = 0; o < 384; o++) s += r[o] * wvq[o];
        wzv[c] = s;
    }
    __syncthreads();
    float a = wzv[tid], b = wzv[tid + 384];
    float s1 = a + b, s2 = a * a + b * b;
    for (int o = 32; o > 0; o >>= 1) { s1 += __shfl_xor(s1, o, 64); s2 += __shfl_xor(s2, o, 64); }
    if (lane == 0) { red[wid] = s1; red[6 + wid] = s2; }
    __syncthreads();
    s1 = 0.f; s2 = 0.f;
    for (int w = 0; w < 6; w++) { s1 += red[w]; s2 += red[6 + w]; }
    float mean = s1 / 768.f, var = s2 / 768.f - mean * mean, rstd = rsqrtf(var + 1e-5f);
    for (int c = tid; c < 768; c += 384) {
        float t = (wzv[c] - mean) * rstd * lng[c] + lnb[c];
        sgate[c] = 1.f / (1.f + expf(-t));
    }
}

__global__ void k_xatt(const float* __restrict__ X, const float* __restrict__ sgate,
                       u16* __restrict__ xatt) {
    size_t i = ((size_t)blockIdx.x * 256 + threadIdx.x) * 4;
    int c = (int)(i % CDIM);
    float4 v = *(const float4*)(X + i);
    u16 o[4] = {f2bf(v.x * sgate[c]), f2bf(v.y * sgate[c + 1]),
                f2bf(v.z * sgate[c + 2]), f2bf(v.w * sgate[c + 3])};
    *(uint2*)(xatt + i) = *(uint2*)o;
}

__global__ void k_colmax(const float* __restrict__ P2, float* __restrict__ m2) {
    __shared__ float red[8][64];
    int o = blockIdx.x * 64 + threadIdx.x;
    float m = -1e30f;
    for (int p = threadIdx.y; p < 4096; p += 8) m = fmaxf(m, P2[(size_t)p * 384 + o]);
    red[threadIdx.y][threadIdx.x] = m;
    __syncthreads();
    if (threadIdx.y == 0) {
        for (int y = 1; y < 8; y++) m = fmaxf(m, red[y][threadIdx.x]);
        m2[o] = m;
    }
}

__global__ void k_cam7(const float* __restrict__ m2, const float* __restrict__ spv,
                       float* __restrict__ sv) {
    __shared__ float sq2[384];
    __shared__ float red[6];
    int tid = threadIdx.x, lane = tid & 63, wid = tid >> 6;
    float v = m2[tid];
    float m = v;
    for (int o = 32; o > 0; o >>= 1) m = fmaxf(m, __shfl_xor(m, o, 64));
    if (lane == 0) red[wid] = m;
    __syncthreads();
    m = red[0];
    for (int w = 1; w < 6; w++) m = fmaxf(m, red[w]);
    __syncthreads();
    float e = expf(v - m);
    float s = e;
    for (int o = 32; o > 0; o >>= 1) s += __shfl_xor(s, o, 64);
    if (lane == 0) red[wid] = s;
    __syncthreads();
    float tot = 0.f;
    for (int w = 0; w < 6; w++) tot += red[w];
    sq2[tid] = e / tot;
    __syncthreads();
    for (int c = tid; c < 768; c += 384) {
        float a = 0.f;
        for (int o = 0; o < 384; o++) a += sq2[o] * spv[(size_t)o * 768 + c];
        sv[c] = a;
    }
}

__global__ void k_final(const float* __restrict__ X, const float* __restrict__ x5,
                        const float* __restrict__ sgate, const float* __restrict__ sv,
                        const float* __restrict__ ng, const float* __restrict__ nb,
                        float* __restrict__ out) {
    int wid = threadIdx.x >> 6, lane = threadIdx.x & 63;
    int p = blockIdx.x * 4 + wid;
    const float* xr = X + (size_t)p * CDIM;
    const float* x5r = x5 + (size_t)p * CDIM;
    float xa[12];
    float d = 0.f;
#pragma unroll
    for (int j = 0; j < 12; j++) {
        int c = lane + 64 * j;
        float a = xr[c] * sgate[c];
        xa[j] = a;
        d += sv[c] * a;
    }
#pragma unroll
    for (int o = 32; o > 0; o >>= 1) d += __shfl_xor(d, o, 64);
    float wz2 = 1.f / (1.f + expf(-d));
    float s1 = 0.f, s2 = 0.f;
#pragma unroll
    for (int j = 0; j < 12; j++) {
        int c = lane + 64 * j;
        float y = wz2 * xa[j] + xr[c] + x5r[c];
        xa[j] = y;
        s1 += y; s2 += y * y;
    }
#pragma unroll
    for (int o = 32; o > 0; o >>= 1) { s1 += __shfl_xor(s1, o, 64); s2 += __shfl_xor(s2, o, 64); }
    float mean = s1 / 768.f, var = s2 / 768.f - mean * mean, rstd = rsqrtf(var + 1e-5f);
#pragma unroll
    for (int j = 0; j < 12; j++) {
        int c = lane + 64 * j;
        out[(size_t)p * CDIM + c] = (xa[j] - mean) * rstd * ng[c] + nb[c];
    }
}

// ---------------------------------------------------------------- launch
extern "C" void kernel_launch(void* const* d_in, const int* in_sizes, int n_in,
                              void* d_out, int out_size, void* d_ws, size_t ws_size,
                              hipStream_t stream) {
    const float* xin[5];
    for (int i = 0; i < 5; i++) xin[i] = (const float*)d_in[i];
    const float* conv_w = (const float*)d_in[5];
    const float* conv_b = (const float*)d_in[6];
    const float* off_w = (const float*)d_in[7];
    const float* off_b = (const float*)d_in[8];
    const float* msk_w = (const float*)d_in[9];
    const float* msk_b = (const float*)d_in[10];
    const float* bn_g = (const float*)d_in[11];
    const float* bn_b = (const float*)d_in[12];
    const float* chq_w = (const float*)d_in[13];
    const float* chv_w = (const float*)d_in[14];
    const float* chz_w = (const float*)d_in[15];
    const float* ln_g = (const float*)d_in[16];
    const float* ln_b = (const float*)d_in[17];
    const float* spq_w = (const float*)d_in[18];
    const float* spv_w = (const float*)d_in[19];
    const float* wsrc[8];
    for (int i = 0; i < 8; i++) wsrc[i] = (const float*)d_in[20 + i];
    const float* norm_g = (const float*)d_in[28];
    const float* norm_b = (const float*)d_in[29];
    float* out = (float*)d_out;

    char* wsb = (char*)d_ws;
    size_t off = 0;
    auto take = [&](size_t n) -> char* {
        char* p = wsb + off;
        off = (off + n + 255) & ~(size_t)255;
        return p;
    };
    u16* xb = (u16*)take(5ll * HW * CDIM * 2);
    u16* Wt = (u16*)take(9ll * CDIM * CDIM * 2);
    u16* omblk = (u16*)take(5ll * HW * CDIM * 2);  // om, later reused as blk
    float* offs = (float*)take(5ll * HW * 18 * 4);
    float* msoft = (float*)take(5ll * 36864 * 4);
    int4* idx4 = (int4*)take(5ll * 9 * 4096 * 16);
    float4* w4 = (float4*)take(5ll * 9 * 4096 * 16);
    u16* dout = (u16*)take(5ll * HW * CDIM * 2);   // later reused: xatt @+0, P2 @+8MB
    u16* wb = (u16*)take(1790ll * 768 * 2);
    float* Xcat = (float*)take((size_t)HW * CDIM * 4);
    float* mu = (float*)take(5 * 768 * 4);
    float* rs = (float*)take(5 * 768 * 4);
    float* qv = (float*)take(4096 * 4);
    float* sqn = (float*)take(4096 * 4);
    float* xq = (float*)take(768 * 4);
    float* sgate = (float*)take(768 * 4);
    float* m2 = (float*)take(384 * 4);
    float* sv = (float*)take(768 * 4);
    u16* xatt = dout;
    float* P2 = (float*)((char*)dout + 8388608);
    u16* blk = omblk;
    (void)ws_size; (void)in_sizes; (void)n_in; (void)out_size; (void)bn_g;

    // weight copy table: w1,w2,w3a,w3b,w4a,w4b,w5a,w5b,spq
    int rows[9] = {30, 100, 150, 150, 220, 220, 268, 268, 384};
    int roff[9]; int acc = 0;
    for (int i = 0; i < 9; i++) { roff[i] = acc; acc += rows[i]; }
    u16* spqb = wb + (size_t)roff[8] * 768;

    WbP wp;
    for (int i = 0; i < 8; i++) { wp.src[i] = wsrc[i]; wp.dst[i] = wb + (size_t)roff[i] * 768; wp.n[i] = rows[i] * 768; }
    wp.src[8] = spq_w; wp.dst[8] = spqb; wp.n[8] = rows[8] * 768;

    ProjP pp;
    pp.b1[0] = wb + (size_t)roff[0] * 768; pp.b2[0] = nullptr;
    pp.b1[1] = wb + (size_t)roff[1] * 768; pp.b2[1] = nullptr;
    pp.b1[2] = wb + (size_t)roff[2] * 768; pp.b2[2] = wb + (size_t)roff[3] * 768;
    pp.b1[3] = wb + (size_t)roff[4] * 768; pp.b2[3] = wb + (size_t)roff[5] * 768;
    pp.b1[4] = wb + (size_t)roff[6] * 768; pp.b2[4] = wb + (size_t)roff[7] * 768;
    int chs[5] = {30, 100, 150, 220, 268};
    int cof[5] = {0, 30, 130, 280, 500};
    for (int i = 0; i < 5; i++) { pp.ch[i] = chs[i]; pp.choff[i] = cof[i]; }
    ProjP pdum = {};

    Ptr5 xs;
    for (int i = 0; i < 5; i++) xs.p[i] = xin[i];

    // ---- prep ----
    k_prep_x<<<dim3(1536, 5), 256, 0, stream>>>(xs, xb);
    k_prep_wt<<<dim3(768), 256, 0, stream>>>(conv_w, Wt);
    k_prep_wb<<<dim3(288, 9), 256, 0, stream>>>(wp);

    // ---- per-level heavy path (batched over z=5) ----
    k_gemm<G_CONV><<<dim3(32, 6, 5), 256, 0, stream>>>(xb, nullptr, Wt, nullptr, nullptr,
                                                       conv_b, omblk, nullptr, pdum);
    k_offmask1<<<dim3(1024, 5), 256, 0, stream>>>(omblk, off_w, off_b, msk_w, msk_b, offs, msoft);
    k_offmask2<<<dim3(720), 256, 0, stream>>>(offs, msoft, idx4, w4);
    k_gemm<G_DEFORM><<<dim3(32, 6, 5), 256, 0, stream>>>(xb, nullptr, Wt, idx4, w4,
                                                         conv_b, dout, nullptr, pdum);
    k_bnstats<<<dim3(12, 5), dim3(64, 8), 0, stream>>>(dout, mu, rs);
    k_bnapply<<<dim3(7680), 256, 0, stream>>>(dout, mu, rs, bn_g, bn_b, blk);
    k_gemm<G_PROJ><<<dim3(32, 3, 5), 256, 0, stream>>>(xb, blk, nullptr, nullptr, nullptr,
                                                       nullptr, nullptr, Xcat, pp);

    // ---- CAM ----
    k_q<<<dim3(1024), 256, 0, stream>>>(Xcat, chq_w, qv);
    k_soft4096<<<dim3(1), 256, 0, stream>>>(qv, sqn, xq);
    k_xq<<<dim3(8), 256, 0, stream>>>(Xcat, sqn, xq);
    k_cam4<<<dim3(1), 384, 0, stream>>>(chv_w, chz_w, xq, ln_g, ln_b, sgate);
    k_xatt<<<dim3(3072), 256, 0, stream>>>(Xcat, sgate, xatt);
    k_gemm<G_SPAT><<<dim3(32, 3, 1), 256, 0, stream>>>(nullptr, xatt, spqb, nullptr, nullptr,
                                                       nullptr, nullptr, P2, pdum);
    k_colmax<<<dim3(6), dim3(64, 8), 0, stream>>>(P2, m2);
    k_cam7<<<dim3(1), 384, 0, stream>>>(m2, spv_w, sv);

    // ---- residual + final LayerNorm ----
    k_final<<<dim3(1024), 256, 0, stream>>>(Xcat, xin[4], sgate, sv, norm_g, norm_b, out);
}

// Round 2
// 1432.779 us; speedup vs baseline: 1.3849x; 1.3849x over previous
//
#include <hip/hip_runtime.h>
#include <cstdint>
#include <cstddef>

#define HW 4096
#define CDIM 768
#define PPIX 4356   // 66*66 padded pixels

typedef unsigned short u16;
typedef __attribute__((ext_vector_type(8))) short short8;
typedef __attribute__((ext_vector_type(4))) float f32x4;

__device__ __forceinline__ float bf2f(u16 u) { return __uint_as_float(((unsigned)u) << 16); }
__device__ __forceinline__ u16 f2bf(float f) {
    unsigned u = __float_as_uint(f);
    unsigned r = (u + 0x7fffu + ((u >> 16) & 1u)) >> 16;
    return (u16)r;
}
__device__ __forceinline__ float lof(unsigned u) { return __uint_as_float(u << 16); }
__device__ __forceinline__ float hif(unsigned u) { return __uint_as_float(u & 0xffff0000u); }
__device__ __forceinline__ unsigned pkbf(float lo, float hi) {
    return (unsigned)f2bf(lo) | ((unsigned)f2bf(hi) << 16);
}
__device__ __forceinline__ int swz(int r) { return ((r >> 1) ^ (r >> 3)) & 3; }

__device__ __forceinline__ void gl16(const u16* g, u16* l) {
    __builtin_amdgcn_global_load_lds(
        (const __attribute__((address_space(1))) unsigned int*)g,
        (__attribute__((address_space(3))) unsigned int*)l, 16, 0, 0);
}

// ---------------------------------------------------------------- GEMM core
// C[4096, N] = A[4096, K] @ B^T, B row-major [N][768-per-sub] bf16.
// Tile 128x256, BK=32, 256 threads = 4 waves (2x2), wave tile 64x128 (4x8 frags).
// LDS layout: packed [rows][4 chunks of 16B], chunk position = srcchunk ^ swz(row).
enum GMode { G_CONV = 0, G_DEFORM = 1, G_PROJ = 2, G_SPAT = 3 };

struct ProjP {
    const u16* b1[5];
    const u16* b2[5];
    int ch[5];
    int choff[5];
};

template <int MODE>
__launch_bounds__(256, 2)
__global__ void k_gemm(const u16* __restrict__ xpad,  // [5][4356][768] bf16 padded image
                       const u16* __restrict__ blkA,  // proj A1 (blk) / spat A (xatt)
                       const u16* __restrict__ Wt,    // conv/deform B [9][768][768] / spat B
                       const int4* __restrict__ idx4, // [5][9][4096] padded row offsets (pre *768)
                       const float4* __restrict__ w4, // [5][9][4096] fused weights
                       const float* __restrict__ bias,
                       u16* __restrict__ outb,        // bf16 out (om / dout)
                       float* __restrict__ outf,      // fp32 out (Xcat / P2)
                       ProjP pp) {
    const int z = blockIdx.z;
    const int m0 = blockIdx.x * 128;
    const int n0 = blockIdx.y * 256;

    int Nrows, ntap, choff = 0, ldo = CDIM;
    const u16 *Az = nullptr, *Ac = nullptr, *B1 = nullptr, *B2 = nullptr;
    const int4* idxz = nullptr;
    const float4* w4z = nullptr;

    if constexpr (MODE == G_CONV) {
        Az = xpad + (size_t)z * PPIX * CDIM; B1 = Wt; Nrows = 768; ntap = 9;
    } else if constexpr (MODE == G_DEFORM) {
        Az = xpad + (size_t)z * PPIX * CDIM; B1 = Wt; Nrows = 768; ntap = 9;
        idxz = idx4 + (size_t)z * 9 * 4096;
        w4z = w4 + (size_t)z * 9 * 4096;
    } else if constexpr (MODE == G_PROJ) {
        Ac = blkA + (size_t)z * HW * CDIM;            // sub0: BN'd block output
        Az = xpad + (size_t)z * PPIX * CDIM;          // sub1: original x (center tap)
        B1 = pp.b1[z]; B2 = pp.b2[z];
        Nrows = pp.ch[z]; choff = pp.choff[z];
        ntap = B2 ? 2 : 1;
        if (n0 >= Nrows) return;
    } else { // G_SPAT
        Ac = blkA; B1 = Wt; Nrows = 384; ntap = 1; ldo = 384;
        if (n0 >= Nrows) return;
    }

    __shared__ __align__(16) u16 As[128 * 32];
    __shared__ __align__(16) u16 Bs[256 * 32];

    const int t = threadIdx.x;
    const int lane = t & 63;
    const int wid = t >> 6;
    const int wrow = (wid >> 1) * 64, wcol = (wid & 1) * 128;
    const int lm = lane & 15;
    const int quad = lane >> 4;

    // staging destination bases (wave-uniform)
    u16* dstA0 = &As[(0 * 4 + wid) * 512];
    u16* dstA1 = &As[(1 * 4 + wid) * 512];
    u16* dstB[4];
#pragma unroll
    for (int c = 0; c < 4; c++) dstB[c] = &Bs[(c * 4 + wid) * 512];

    // A staging source row/chunk per call (non-deform)
    int rA[2], csA[2];
#pragma unroll
    for (int c = 0; c < 2; c++) {
        rA[c] = c * 64 + (t >> 2);
        csA[c] = (t & 3) ^ swz(rA[c]);
    }
    // B staging row/chunk per call
    int rB[4], csB[4];
#pragma unroll
    for (int c = 0; c < 4; c++) {
        rB[c] = c * 64 + (t >> 2);
        csB[c] = (t & 3) ^ swz(rB[c]);
    }
    // deform: per-thread row + chunk pair
    const int rD = t >> 1, jD = t & 1, sD = swz(t >> 1);
    u16* wdst0 = &As[rD * 32 + ((2 * jD) ^ sD) * 8];
    u16* wdst1 = &As[rD * 32 + ((2 * jD + 1) ^ sD) * 8];

    f32x4 acc[4][8];
#pragma unroll
    for (int i = 0; i < 4; i++)
#pragma unroll
        for (int j = 0; j < 8; j++) acc[i][j] = (f32x4){0.f, 0.f, 0.f, 0.f};

    for (int sub = 0; sub < ntap; ++sub) {
        // ---- per-sub setup ----
        const u16* aP[2];
        const u16 *d0 = nullptr, *d1 = nullptr, *d2 = nullptr, *d3 = nullptr;
        float4 wv = make_float4(0.f, 0.f, 0.f, 0.f);
        if constexpr (MODE == G_DEFORM) {
            int4 iv = idxz[sub * 4096 + m0 + rD];
            wv = w4z[sub * 4096 + m0 + rD];
            d0 = Az + iv.x + jD * 16;
            d1 = Az + iv.y + jD * 16;
            d2 = Az + iv.z + jD * 16;
            d3 = Az + iv.w + jD * 16;
        } else {
            int ky = 1, kx = 1;
            bool pixmap;
            if constexpr (MODE == G_CONV) { ky = sub / 3; kx = sub % 3; pixmap = true; }
            else if constexpr (MODE == G_PROJ) { pixmap = (sub == 1); }
            else { pixmap = false; }
#pragma unroll
            for (int c = 0; c < 2; c++) {
                int p = m0 + rA[c];
                if (pixmap) {
                    int h = p >> 6, w = p & 63;
                    int pidx = (h + ky) * 66 + (w + kx);
                    aP[c] = Az + (size_t)pidx * CDIM + csA[c] * 8;
                } else {
                    const u16* Ab = Ac;
                    aP[c] = Ab + (size_t)p * CDIM + csA[c] * 8;
                }
            }
        }
        const u16* Bb;
        if constexpr (MODE == G_CONV || MODE == G_DEFORM)
            Bb = B1 + (size_t)sub * CDIM * CDIM;
        else if constexpr (MODE == G_PROJ)
            Bb = (sub == 0) ? B1 : B2;
        else
            Bb = B1;
        const u16* bP[4];
#pragma unroll
        for (int c = 0; c < 4; c++) bP[c] = Bb + (size_t)(n0 + rB[c]) * CDIM + csB[c] * 8;

        for (int kk = 0; kk < 24; ++kk) {
            const int cb = kk * 32;
            __syncthreads();
            // ---- stage A ----
            if constexpr (MODE == G_DEFORM) {
                uint4 s0a = *(const uint4*)(d0 + cb), s0b = *(const uint4*)(d0 + cb + 8);
                uint4 s1a = *(const uint4*)(d1 + cb), s1b = *(const uint4*)(d1 + cb + 8);
                uint4 s2a = *(const uint4*)(d2 + cb), s2b = *(const uint4*)(d2 + cb + 8);
                uint4 s3a = *(const uint4*)(d3 + cb), s3b = *(const uint4*)(d3 + cb + 8);
                auto blw = [&](unsigned u0, unsigned u1, unsigned u2, unsigned u3) -> unsigned {
                    float lo = wv.x * lof(u0) + wv.y * lof(u1) + wv.z * lof(u2) + wv.w * lof(u3);
                    float hi = wv.x * hif(u0) + wv.y * hif(u1) + wv.z * hif(u2) + wv.w * hif(u3);
                    return pkbf(lo, hi);
                };
                uint4 o0, o1;
                o0.x = blw(s0a.x, s1a.x, s2a.x, s3a.x);
                o0.y = blw(s0a.y, s1a.y, s2a.y, s3a.y);
                o0.z = blw(s0a.z, s1a.z, s2a.z, s3a.z);
                o0.w = blw(s0a.w, s1a.w, s2a.w, s3a.w);
                o1.x = blw(s0b.x, s1b.x, s2b.x, s3b.x);
                o1.y = blw(s0b.y, s1b.y, s2b.y, s3b.y);
                o1.z = blw(s0b.z, s1b.z, s2b.z, s3b.z);
                o1.w = blw(s0b.w, s1b.w, s2b.w, s3b.w);
                *(uint4*)wdst0 = o0;
                *(uint4*)wdst1 = o1;
            } else {
                gl16(aP[0] + cb, dstA0);
                gl16(aP[1] + cb, dstA1);
            }
            // ---- stage B ----
            gl16(bP[0] + cb, dstB[0]);
            gl16(bP[1] + cb, dstB[1]);
            gl16(bP[2] + cb, dstB[2]);
            gl16(bP[3] + cb, dstB[3]);
            __syncthreads();
            // ---- MFMA ----
            short8 af[4], bf[8];
#pragma unroll
            for (int i = 0; i < 4; i++) {
                int rr = wrow + i * 16 + lm;
                af[i] = *(const short8*)&As[rr * 32 + ((quad ^ swz(rr)) * 8)];
            }
#pragma unroll
            for (int j = 0; j < 8; j++) {
                int rr = wcol + j * 16 + lm;
                bf[j] = *(const short8*)&Bs[rr * 32 + ((quad ^ swz(rr)) * 8)];
            }
#pragma unroll
            for (int i = 0; i < 4; i++)
#pragma unroll
                for (int j = 0; j < 8; j++)
                    acc[i][j] = __builtin_amdgcn_mfma_f32_16x16x32_bf16(af[i], bf[j], acc[i][j], 0, 0, 0);
        }
    }

    // ---- epilogue ----
    if constexpr (MODE == G_CONV || MODE == G_DEFORM) {
        u16* outz = outb + (size_t)z * HW * CDIM;
#pragma unroll
        for (int j = 0; j < 8; j++) {
            int gc = n0 + wcol + j * 16 + lm;
            float bv = bias[gc];
#pragma unroll
            for (int i = 0; i < 4; i++)
#pragma unroll
                for (int r = 0; r < 4; r++) {
                    int gr = m0 + wrow + i * 16 + quad * 4 + r;
                    outz[(size_t)gr * CDIM + gc] = f2bf(acc[i][j][r] + bv);
                }
        }
    } else {
#pragma unroll
        for (int j = 0; j < 8; j++) {
            int gc = n0 + wcol + j * 16 + lm;
            if (gc < Nrows) {
#pragma unroll
                for (int i = 0; i < 4; i++)
#pragma unroll
                    for (int r = 0; r < 4; r++) {
                        int gr = m0 + wrow + i * 16 + quad * 4 + r;
                        outf[(size_t)gr * ldo + choff + gc] = acc[i][j][r];
                    }
            }
        }
    }
}

// ---------------------------------------------------------------- prep kernels
struct Ptr5 { const float* p[5]; };

// build zero-padded bf16 image [5][66][66][768]
__global__ void k_prep_xpad(Ptr5 xs, u16* __restrict__ xpad) {
    int z = blockIdx.y;
    int pidx = blockIdx.x;
    int ph = pidx / 66, pw = pidx - ph * 66;
    int e0 = threadIdx.x * 4;
    u16* d = xpad + ((size_t)z * PPIX + pidx) * CDIM + e0;
    if (ph == 0 || ph == 65 || pw == 0 || pw == 65) {
        *(uint2*)d = make_uint2(0, 0);
        return;
    }
    const float* s = xs.p[z] + ((size_t)((ph - 1) * 64 + (pw - 1))) * CDIM + e0;
    float4 v = *(const float4*)s;
    u16 o[4] = {f2bf(v.x), f2bf(v.y), f2bf(v.z), f2bf(v.w)};
    *(uint2*)d = *(uint2*)o;
}

__global__ void k_prep_wt(const float* __restrict__ cw, u16* __restrict__ Wt) {
    int o = blockIdx.x;
    for (int c = threadIdx.x; c < 768; c += 256) {
        const float* s = cw + ((size_t)o * 768 + c) * 9;
#pragma unroll
        for (int k = 0; k < 9; k++)
            Wt[(size_t)k * 768 * 768 + (size_t)o * 768 + c] = f2bf(s[k]);
    }
}

struct WbP { const float* src[9]; u16* dst[9]; int n[9]; };

__global__ void k_prep_wb(WbP wp) {
    int m = blockIdx.y;
    int i = (blockIdx.x * 256 + threadIdx.x) * 4;
    if (i >= wp.n[m]) return;
    float4 v = *(const float4*)(wp.src[m] + i);
    u16* d = wp.dst[m] + i;
    d[0] = f2bf(v.x); d[1] = f2bf(v.y); d[2] = f2bf(v.z); d[3] = f2bf(v.w);
}

// ---------------------------------------------------------------- offset / mask
__global__ void k_offmask1(const u16* __restrict__ om, const float* __restrict__ off_w,
                           const float* __restrict__ off_b, const float* __restrict__ msk_w,
                           const float* __restrict__ msk_b, float* __restrict__ offs,
                           float* __restrict__ msoft) {
    int z = blockIdx.y;
    int wid = threadIdx.x >> 6, lane = threadIdx.x & 63;
    int p = blockIdx.x * 4 + wid;
    const u16* r = om + (size_t)z * HW * CDIM + (size_t)p * CDIM;
    float v[12];
#pragma unroll
    for (int j = 0; j < 12; j++) v[j] = bf2f(r[lane + 64 * j]);
    float lg[9];
#pragma unroll
    for (int qq = 0; qq < 27; qq++) {
        const float* wr = (qq < 18) ? (off_w + qq * 768) : (msk_w + (qq - 18) * 768);
        float s = 0.f;
#pragma unroll
        for (int j = 0; j < 12; j++) s += v[j] * wr[lane + 64 * j];
#pragma unroll
        for (int o = 32; o > 0; o >>= 1) s += __shfl_xor(s, o, 64);
        if (qq < 18) {
            if (lane == qq) offs[((size_t)z * HW + p) * 18 + qq] = s + off_b[qq];
        } else {
            lg[qq - 18] = s + msk_b[qq - 18];
        }
    }
    float mx = -1e30f;
#pragma unroll
    for (int j = 0; j < 9; j++) mx = fmaxf(mx, lg[j]);
    float sum = 0.f;
#pragma unroll
    for (int j = 0; j < 9; j++) { lg[j] = expf(lg[j] - mx); sum += lg[j]; }
    float inv = 1.f / sum;
#pragma unroll
    for (int j = 0; j < 9; j++)
        if (lane == j) msoft[(size_t)z * 36864 + p * 9 + j] = lg[j] * inv;
}

__device__ __forceinline__ int cidx(int y, int x) {
    int yc = min(max(y, 0), 63), xc = min(max(x, 0), 63);
    return ((yc + 1) * 66 + (xc + 1)) * CDIM;   // padded-image offset
}
__device__ __forceinline__ float cval(int y, int x) {
    return (y >= 0 && y < 64 && x >= 0 && x < 64) ? 1.f : 0.f;
}

__global__ void k_offmask2(const float* __restrict__ offs, const float* __restrict__ msoft,
                           int4* __restrict__ idx4o, float4* __restrict__ w4o) {
    int id = blockIdx.x * 256 + threadIdx.x;
    int z = id / 36864, r = id % 36864, k = r >> 12, p = r & 4095;
    const float* ofz = offs + ((size_t)z * HW + p) * 18;
    float dy = ofz[2 * k], dx = ofz[2 * k + 1];
    float mk = msoft[(size_t)z * 36864 + k * 4096 + p];
    int h = p >> 6, w = p & 63;
    float py = (float)(h - 1 + k / 3) + dy;
    float px = (float)(w - 1 + k % 3) + dx;
    float y0f = floorf(py), x0f = floorf(px);
    int y0 = (int)y0f, x0 = (int)x0f;
    float wy1 = py - y0f, wx1 = px - x0f, wy0 = 1.f - wy1, wx0 = 1.f - wx1;
    idx4o[id] = make_int4(cidx(y0, x0), cidx(y0, x0 + 1), cidx(y0 + 1, x0), cidx(y0 + 1, x0 + 1));
    w4o[id] = make_float4(wy0 * wx0 * cval(y0, x0) * mk, wy0 * wx1 * cval(y0, x0 + 1) * mk,
                          wy1 * wx0 * cval(y0 + 1, x0) * mk, wy1 * wx1 * cval(y0 + 1, x0 + 1) * mk);
}

// ---------------------------------------------------------------- batchnorm
__global__ void k_bnstats(const u16* __restrict__ dout, float* __restrict__ mu,
                          float* __restrict__ rs) {
    int z = blockIdx.y;
    int c = blockIdx.x * 64 + threadIdx.x;
    int ty = threadIdx.y;
    const u16* d = dout + (size_t)z * HW * CDIM + c;
    float s1 = 0.f, s2 = 0.f;
    for (int p = ty; p < 4096; p += 8) {
        float v = bf2f(d[(size_t)p * CDIM]);
        s1 += v; s2 += v * v;
    }
    __shared__ float l1[8][64], l2[8][64];
    l1[ty][threadIdx.x] = s1; l2[ty][threadIdx.x] = s2;
    __syncthreads();
    if (ty == 0) {
        for (int y = 1; y < 8; y++) { s1 += l1[y][threadIdx.x]; s2 += l2[y][threadIdx.x]; }
        float m = s1 / 4096.f;
        float var = s2 / 4096.f - m * m;
        mu[z * 768 + c] = m;
        rs[z * 768 + c] = rsqrtf(var + 1e-5f);
    }
}

__global__ void k_bnapply(const u16* __restrict__ dout, const float* __restrict__ mu,
                          const float* __restrict__ rs, const float* __restrict__ g,
                          const float* __restrict__ b, u16* __restrict__ blk) {
    size_t i = ((size_t)blockIdx.x * 256 + threadIdx.x) * 8;
    int c = (int)(i % CDIM);
    int z = (int)(i / ((size_t)HW * CDIM));
    const float* muz = mu + z * 768;
    const float* rsz = rs + z * 768;
    uint4 in = *(const uint4*)(dout + i);
    const u16* u = (const u16*)&in;
    u16 o[8];
#pragma unroll
    for (int e = 0; e < 8; e++) {
        int ce = c + e;
        float v = (bf2f(u[e]) - muz[ce]) * rsz[ce] * g[ce] + b[ce];
        o[e] = f2bf(fmaxf(v, 0.f));
    }
    *(uint4*)(blk + i) = *(uint4*)o;
}

// ---------------------------------------------------------------- CAM
__global__ void k_q(const float* __restrict__ X, const float* __restrict__ chq,
                    float* __restrict__ q) {
    int wid = threadIdx.x >> 6, lane = threadIdx.x & 63;
    int p = blockIdx.x * 4 + wid;
    const float* xr = X + (size_t)p * CDIM;
    float s = 0.f;
#pragma unroll
    for (int j = 0; j < 12; j++) s += xr[lane + 64 * j] * chq[lane + 64 * j];
#pragma unroll
    for (int o = 32; o > 0; o >>= 1) s += __shfl_xor(s, o, 64);
    if (lane == 0) q[p] = s;
}

__global__ void k_soft4096(const float* __restrict__ q, float* __restrict__ sqn,
                           float* __restrict__ xq) {
    __shared__ float red[4];
    int tid = threadIdx.x, lane = tid & 63, wid = tid >> 6;
    float m = -1e30f;
    for (int i = tid; i < 4096; i += 256) m = fmaxf(m, q[i]);
    for (int o = 32; o > 0; o >>= 1) m = fmaxf(m, __shfl_xor(m, o, 64));
    if (lane == 0) red[wid] = m;
    __syncthreads();
    float bm = fmaxf(fmaxf(red[0], red[1]), fmaxf(red[2], red[3]));
    __syncthreads();
    float s = 0.f;
    for (int i = tid; i < 4096; i += 256) {
        float e = expf(q[i] - bm);
        sqn[i] = e; s += e;
    }
    for (int o = 32; o > 0; o >>= 1) s += __shfl_xor(s, o, 64);
    if (lane == 0) red[wid] = s;
    __syncthreads();
    float inv = 1.f / (red[0] + red[1] + red[2] + red[3]);
    for (int i = tid; i < 4096; i += 256) sqn[i] *= inv;
    for (int c = tid; c < 768; c += 256) xq[c] = 0.f;
}

__global__ void k_xq(const float* __restrict__ X, const float* __restrict__ sqn,
                     float* __restrict__ xq) {
    int p0 = blockIdx.x * 512;
    for (int c = threadIdx.x; c < 768; c += 256) {
        float a = 0.f;
        for (int p = p0; p < p0 + 512; p++) a += sqn[p] * X[(size_t)p * CDIM + c];
        atomicAdd(&xq[c], a);
    }
}

__global__ void k_cam4(const float* __restrict__ chv, const float* __restrict__ chz,
                       const float* __restrict__ xq, const float* __restrict__ lng,
                       const float* __restrict__ lnb, float* __restrict__ sgate) {
    __shared__ float wvq[384];
    __shared__ float wzv[768];
    __shared__ float red[12];
    int tid = threadIdx.x, lane = tid & 63, wid = tid >> 6;
    {
        float s = 0.f;
        const float* r = chv + (size_t)tid * 768;
        for (int j = 0; j < 768; j++) s += r[j] * xq[j];
        wvq[tid] = s;
    }
    __syncthreads();
    for (int c = tid; c < 768; c += 384) {
        float s = 0.f;
        const float* r = chz + (size_t)c * 384;
        for (int o = 0; o < 384; o++) s += r[o] * wvq[o];
        wzv[c] = s;
    }
    __syncthreads();
    float a = wzv[tid], b = wzv[tid + 384];
    float s1 = a + b, s2 = a * a + b * b;
    for (int o = 32; o > 0; o >>= 1) { s1 += __shfl_xor(s1, o, 64); s2 += __shfl_xor(s2, o, 64); }
    if (lane == 0) { red[wid] = s1; red[6 + wid] = s2; }
    __syncthreads();
    s1 = 0.f; s2 = 0.f;
    for (int w = 0; w < 6; w++) { s1 += red[w]; s2 += red[6 + w]; }
    float mean = s1 / 768.f, var = s2 / 768.f - mean * mean, rstd = rsqrtf(var + 1e-5f);
    for (int c = tid; c < 768; c += 384) {
        float t = (wzv[c] - mean) * rstd * lng[c] + lnb[c];
        sgate[c] = 1.f / (1.f + expf(-t));
    }
}

__global__ void k_xatt(const float* __restrict__ X, const float* __restrict__ sgate,
                       u16* __restrict__ xatt) {
    size_t i = ((size_t)blockIdx.x * 256 + threadIdx.x) * 4;
    int c = (int)(i % CDIM);
    float4 v = *(const float4*)(X + i);
    u16 o[4] = {f2bf(v.x * sgate[c]), f2bf(v.y * sgate[c + 1]),
                f2bf(v.z * sgate[c + 2]), f2bf(v.w * sgate[c + 3])};
    *(uint2*)(xatt + i) = *(uint2*)o;
}

__global__ void k_colmax(const float* __restrict__ P2, float* __restrict__ m2) {
    __shared__ float red[8][64];
    int o = blockIdx.x * 64 + threadIdx.x;
    float m = -1e30f;
    for (int p = threadIdx.y; p < 4096; p += 8) m = fmaxf(m, P2[(size_t)p * 384 + o]);
    red[threadIdx.y][threadIdx.x] = m;
    __syncthreads();
    if (threadIdx.y == 0) {
        for (int y = 1; y < 8; y++) m = fmaxf(m, red[y][threadIdx.x]);
        m2[o] = m;
    }
}

__global__ void k_cam7(const float* __restrict__ m2, const float* __restrict__ spv,
                       float* __restrict__ sv) {
    __shared__ float sq2[384];
    __shared__ float red[6];
    int tid = threadIdx.x, lane = tid & 63, wid = tid >> 6;
    float v = m2[tid];
    float m = v;
    for (int o = 32; o > 0; o >>= 1) m = fmaxf(m, __shfl_xor(m, o, 64));
    if (lane == 0) red[wid] = m;
    __syncthreads();
    m = red[0];
    for (int w = 1; w < 6; w++) m = fmaxf(m, red[w]);
    __syncthreads();
    float e = expf(v - m);
    float s = e;
    for (int o = 32; o > 0; o >>= 1) s += __shfl_xor(s, o, 64);
    if (lane == 0) red[wid] = s;
    __syncthreads();
    float tot = 0.f;
    for (int w = 0; w < 6; w++) tot += red[w];
    sq2[tid] = e / tot;
    __syncthreads();
    for (int c = tid; c < 768; c += 384) {
        float a = 0.f;
        for (int o = 0; o < 384; o++) a += sq2[o] * spv[(size_t)o * 768 + c];
        sv[c] = a;
    }
}

__global__ void k_final(const float* __restrict__ X, const float* __restrict__ x5,
                        const float* __restrict__ sgate, const float* __restrict__ sv,
                        const float* __restrict__ ng, const float* __restrict__ nb,
                        float* __restrict__ out) {
    int wid = threadIdx.x >> 6, lane = threadIdx.x & 63;
    int p = blockIdx.x * 4 + wid;
    const float* xr = X + (size_t)p * CDIM;
    const float* x5r = x5 + (size_t)p * CDIM;
    float xa[12];
    float d = 0.f;
#pragma unroll
    for (int j = 0; j < 12; j++) {
        int c = lane + 64 * j;
        float a = xr[c] * sgate[c];
        xa[j] = a;
        d += sv[c] * a;
    }
#pragma unroll
    for (int o = 32; o > 0; o >>= 1) d += __shfl_xor(d, o, 64);
    float wz2 = 1.f / (1.f + expf(-d));
    float s1 = 0.f, s2 = 0.f;
#pragma unroll
    for (int j = 0; j < 12; j++) {
        int c = lane + 64 * j;
        float y = wz2 * xa[j] + xr[c] + x5r[c];
        xa[j] = y;
        s1 += y; s2 += y * y;
    }
#pragma unroll
    for (int o = 32; o > 0; o >>= 1) { s1 += __shfl_xor(s1, o, 64); s2 += __shfl_xor(s2, o, 64); }
    float mean = s1 / 768.f, var = s2 / 768.f - mean * mean, rstd = rsqrtf(var + 1e-5f);
#pragma unroll
    for (int j = 0; j < 12; j++) {
        int c = lane + 64 * j;
        out[(size_t)p * CDIM + c] = (xa[j] - mean) * rstd * ng[c] + nb[c];
    }
}

// ---------------------------------------------------------------- launch
extern "C" void kernel_launch(void* const* d_in, const int* in_sizes, int n_in,
                              void* d_out, int out_size, void* d_ws, size_t ws_size,
                              hipStream_t stream) {
    const float* xin[5];
    for (int i = 0; i < 5; i++) xin[i] = (const float*)d_in[i];
    const float* conv_w = (const float*)d_in[5];
    const float* conv_b = (const float*)d_in[6];
    const float* off_w = (const float*)d_in[7];
    const float* off_b = (const float*)d_in[8];
    const float* msk_w = (const float*)d_in[9];
    const float* msk_b = (const float*)d_in[10];
    const float* bn_g = (const float*)d_in[11];
    const float* bn_b = (const float*)d_in[12];
    const float* chq_w = (const float*)d_in[13];
    const float* chv_w = (const float*)d_in[14];
    const float* chz_w = (const float*)d_in[15];
    const float* ln_g = (const float*)d_in[16];
    const float* ln_b = (const float*)d_in[17];
    const float* spq_w = (const float*)d_in[18];
    const float* spv_w = (const float*)d_in[19];
    const float* wsrc[8];
    for (int i = 0; i < 8; i++) wsrc[i] = (const float*)d_in[20 + i];
    const float* norm_g = (const float*)d_in[28];
    const float* norm_b = (const float*)d_in[29];
    float* out = (float*)d_out;

    char* wsb = (char*)d_ws;
    size_t off = 0;
    auto take = [&](size_t n) -> char* {
        char* p = wsb + off;
        off = (off + n + 255) & ~(size_t)255;
        return p;
    };
    u16* xpad = (u16*)take(5ll * PPIX * CDIM * 2);
    u16* Wt = (u16*)take(9ll * CDIM * CDIM * 2);
    u16* omblk = (u16*)take(5ll * HW * CDIM * 2);  // om, later reused as blk
    float* offs = (float*)take(5ll * HW * 18 * 4);
    float* msoft = (float*)take(5ll * 36864 * 4);
    int4* idx4 = (int4*)take(5ll * 9 * 4096 * 16);
    float4* w4 = (float4*)take(5ll * 9 * 4096 * 16);
    u16* dout = (u16*)take(5ll * HW * CDIM * 2);   // later reused: xatt @+0, P2 @+8MB
    u16* wb = (u16*)take(1790ll * 768 * 2);
    float* Xcat = (float*)take((size_t)HW * CDIM * 4);
    float* mu = (float*)take(5 * 768 * 4);
    float* rs = (float*)take(5 * 768 * 4);
    float* qv = (float*)take(4096 * 4);
    float* sqn = (float*)take(4096 * 4);
    float* xq = (float*)take(768 * 4);
    float* sgate = (float*)take(768 * 4);
    float* m2 = (float*)take(384 * 4);
    float* sv = (float*)take(768 * 4);
    u16* xatt = dout;
    float* P2 = (float*)((char*)dout + 8388608);
    u16* blk = omblk;
    (void)ws_size; (void)in_sizes; (void)n_in; (void)out_size;

    int rows[9] = {30, 100, 150, 150, 220, 220, 268, 268, 384};
    int roff[9]; int acc = 0;
    for (int i = 0; i < 9; i++) { roff[i] = acc; acc += rows[i]; }
    u16* spqb = wb + (size_t)roff[8] * 768;

    WbP wp;
    for (int i = 0; i < 8; i++) { wp.src[i] = wsrc[i]; wp.dst[i] = wb + (size_t)roff[i] * 768; wp.n[i] = rows[i] * 768; }
    wp.src[8] = spq_w; wp.dst[8] = spqb; wp.n[8] = rows[8] * 768;

    ProjP pp;
    pp.b1[0] = wb + (size_t)roff[0] * 768; pp.b2[0] = nullptr;
    pp.b1[1] = wb + (size_t)roff[1] * 768; pp.b2[1] = nullptr;
    pp.b1[2] = wb + (size_t)roff[2] * 768; pp.b2[2] = wb + (size_t)roff[3] * 768;
    pp.b1[3] = wb + (size_t)roff[4] * 768; pp.b2[3] = wb + (size_t)roff[5] * 768;
    pp.b1[4] = wb + (size_t)roff[6] * 768; pp.b2[4] = wb + (size_t)roff[7] * 768;
    int chs[5] = {30, 100, 150, 220, 268};
    int cof[5] = {0, 30, 130, 280, 500};
    for (int i = 0; i < 5; i++) { pp.ch[i] = chs[i]; pp.choff[i] = cof[i]; }
    ProjP pdum = {};

    Ptr5 xs;
    for (int i = 0; i < 5; i++) xs.p[i] = xin[i];

    // ---- prep ----
    k_prep_xpad<<<dim3(PPIX, 5), 192, 0, stream>>>(xs, xpad);
    k_prep_wt<<<dim3(768), 256, 0, stream>>>(conv_w, Wt);
    k_prep_wb<<<dim3(288, 9), 256, 0, stream>>>(wp);

    // ---- per-level heavy path (batched over z=5) ----
    k_gemm<G_CONV><<<dim3(32, 3, 5), 256, 0, stream>>>(xpad, nullptr, Wt, nullptr, nullptr,
                                                       conv_b, omblk, nullptr, pdum);
    k_offmask1<<<dim3(1024, 5), 256, 0, stream>>>(omblk, off_w, off_b, msk_w, msk_b, offs, msoft);
    k_offmask2<<<dim3(720), 256, 0, stream>>>(offs, msoft, idx4, w4);
    k_gemm<G_DEFORM><<<dim3(32, 3, 5), 256, 0, stream>>>(xpad, nullptr, Wt, idx4, w4,
                                                         conv_b, dout, nullptr, pdum);
    k_bnstats<<<dim3(12, 5), dim3(64, 8), 0, stream>>>(dout, mu, rs);
    k_bnapply<<<dim3(7680), 256, 0, stream>>>(dout, mu, rs, bn_g, bn_b, blk);
    k_gemm<G_PROJ><<<dim3(32, 2, 5), 256, 0, stream>>>(xpad, blk, nullptr, nullptr, nullptr,
                                                       nullptr, nullptr, Xcat, pp);

    // ---- CAM ----
    k_q<<<dim3(1024), 256, 0, stream>>>(Xcat, chq_w, qv);
    k_soft4096<<<dim3(1), 256, 0, stream>>>(qv, sqn, xq);
    k_xq<<<dim3(8), 256, 0, stream>>>(Xcat, sqn, xq);
    k_cam4<<<dim3(1), 384, 0, stream>>>(chv_w, chz_w, xq, ln_g, ln_b, sgate);
    k_xatt<<<dim3(3072), 256, 0, stream>>>(Xcat, sgate, xatt);
    k_gemm<G_SPAT><<<dim3(32, 2, 1), 256, 0, stream>>>(xpad, xatt, spqb, nullptr, nullptr,
                                                       nullptr, nullptr, P2, pdum);
    k_colmax<<<dim3(6), dim3(64, 8), 0, stream>>>(P2, m2);
    k_cam7<<<dim3(1), 384, 0, stream>>>(m2, spv_w, sv);

    // ---- residual + final LayerNorm ----
    k_final<<<dim3(1024), 256, 0, stream>>>(Xcat, xin[4], sgate, sv, norm_g, norm_b, out);
}